// Round 19
// baseline (229.569 us; speedup 1.0000x reference)
//
#include <hip/hip_runtime.h>
#include <hip/hip_fp16.h>

#define DIAGNUM 50000
#define MEDNUM  20000
#define PRONUM  40000
#define FEATDIM 128
#define N1 (DIAGNUM + MEDNUM)   // 70000
#define N2 (PRONUM + MEDNUM)    // 60000
#define NNZ1 1120000
#define NNZ2 960000
#define NTOT (2 * N1 + 2 * N2)            // 260000 concatenated rows
#define NNZTOT (2 * NNZ1 + 2 * NNZ2)      // 4160000 concatenated edges
#define NBUCK ((NTOT + 511) >> 9)         // 508 buckets of 512 rows
#define CAP 8704                           // bucket capacity (mean 8192, +5.7 sigma)
#define L1_THREADS 512
#define L1_CHUNK 8192
#define L1_VITERS (L1_CHUNK / (L1_THREADS * 4))   // 4 iterations of 4 edges
#define L1_BLOCKS ((NNZTOT + L1_CHUNK - 1) / L1_CHUNK)   // 508

#define TOT8 ((DIAGNUM + MEDNUM + PRONUM) * (FEATDIM / 8))   // 1,760,000
#define CONV_BLOCKS ((TOT8 + L1_THREADS - 1) / L1_THREADS)   // 3438 (512-thr)

// fused launch block classes (4 rows/block): d -> med -> p
#define D_BLOCKS (DIAGNUM / 4)   // 12500
#define M_BLOCKS (MEDNUM / 4)    // 5000
#define P_BLOCKS (PRONUM / 4)    // 10000

typedef unsigned short ushort_t;

// ---------------- cursor init (bucket bases are fixed: b*CAP) ----------------
__global__ __launch_bounds__(256) void init_cursor_kernel(int* __restrict__ cursor) {
    int b = blockIdx.x * 256 + threadIdx.x;
    if (b < NBUCK) cursor[b] = b * CAP;
}

// ---------------- fp16 embedding conversion (device fn, shared by 2 kernels) ----------------
// emb1 = [dE; mE] (N1 x 128), emb2 = [pE; mE] (N2 x 128); med rows duplicated.
__device__ __forceinline__ ushort_t f2h(float x) {
    return __half_as_ushort(__float2half(x));
}

__device__ __forceinline__ void convert_t8(int t8,
        const float* __restrict__ dE, const float* __restrict__ mE,
        const float* __restrict__ pE,
        ushort_t* __restrict__ emb1, ushort_t* __restrict__ emb2) {
    long flat = (long)t8 * 8;
    const float* src;
    ushort_t* dst;
    ushort_t* dst2 = nullptr;
    if (flat < (long)DIAGNUM * FEATDIM) {
        src = dE + flat;
        dst = emb1 + flat;
    } else if (flat < (long)(DIAGNUM + MEDNUM) * FEATDIM) {
        long o = flat - (long)DIAGNUM * FEATDIM;
        src = mE + o;
        dst  = emb1 + (long)DIAGNUM * FEATDIM + o;
        dst2 = emb2 + (long)PRONUM * FEATDIM + o;
    } else {
        long o = flat - (long)(DIAGNUM + MEDNUM) * FEATDIM;
        src = pE + o;
        dst = emb2 + o;
    }
    float4 a = *reinterpret_cast<const float4*>(src);
    float4 b = *reinterpret_cast<const float4*>(src + 4);
    int4 w;
    w.x = (int)((unsigned)f2h(a.x) | ((unsigned)f2h(a.y) << 16));
    w.y = (int)((unsigned)f2h(a.z) | ((unsigned)f2h(a.w) << 16));
    w.z = (int)((unsigned)f2h(b.x) | ((unsigned)f2h(b.y) << 16));
    w.w = (int)((unsigned)f2h(b.z) | ((unsigned)f2h(b.w) << 16));
    *reinterpret_cast<int4*>(dst) = w;
    if (dst2) *reinterpret_cast<int4*>(dst2) = w;
}

__global__ __launch_bounds__(256) void convert_emb_kernel(
        const float* __restrict__ dE, const float* __restrict__ mE,
        const float* __restrict__ pE,
        ushort_t* __restrict__ emb1, ushort_t* __restrict__ emb2) {
    int t8 = blockIdx.x * 256 + threadIdx.x;
    if (t8 < TOT8) convert_t8(t8, dE, mE, pE, emb1, emb2);
}

// ---------------- level-1 scatter into fixed-capacity buckets ----------------
// 512 threads x 8192-edge chunks; vector int4/float4 loads; row indices cached
// in registers across sweeps. Blocks >= L1_BLOCKS (big-ws mode only) run the
// embedding conversion instead (separate ws regions -> no race).
// record: .x = (row_local << 17) | col, .y = val bits.
__global__ __launch_bounds__(L1_THREADS) void lvl1_scatter_kernel(
        const int* __restrict__ a1r, const int* __restrict__ a1c,
        const float* __restrict__ a1v,
        const int* __restrict__ a2r, const int* __restrict__ a2c,
        const float* __restrict__ a2v,
        int* __restrict__ cursor, int2* __restrict__ lvl1,
        const float* __restrict__ dE, const float* __restrict__ mE,
        const float* __restrict__ pE,
        ushort_t* __restrict__ emb1, ushort_t* __restrict__ emb2) {
    if (blockIdx.x >= L1_BLOCKS) {
        int t8 = (blockIdx.x - L1_BLOCKS) * L1_THREADS + threadIdx.x;
        if (t8 < TOT8) convert_t8(t8, dE, mE, pE, emb1, emb2);
        return;
    }
    __shared__ int lh[NBUCK];
    for (int b = threadIdx.x; b < NBUCK; b += L1_THREADS) lh[b] = 0;
    __syncthreads();
    int base = blockIdx.x * L1_CHUNK;
    int idxv[L1_VITERS * 4];
#pragma unroll
    for (int it = 0; it < L1_VITERS; it++) {
        int i = base + (it * L1_THREADS + threadIdx.x) * 4;
        if (i < NNZTOT) {
            int4 r4;
            int ofs;
            if (i < 2 * NNZ1) {
                r4 = *reinterpret_cast<const int4*>(a1r + i);
                ofs = (i < NNZ1) ? 0 : N1;
            } else {
                r4 = *reinterpret_cast<const int4*>(a2r + (i - 2 * NNZ1));
                ofs = 2 * N1 + ((i - 2 * NNZ1 < NNZ2) ? 0 : N2);
            }
            int idx0 = ofs + r4.x, idx1 = ofs + r4.y;
            int idx2 = ofs + r4.z, idx3 = ofs + r4.w;
            idxv[it * 4]     = idx0;
            idxv[it * 4 + 1] = idx1;
            idxv[it * 4 + 2] = idx2;
            idxv[it * 4 + 3] = idx3;
            atomicAdd(&lh[idx0 >> 9], 1);
            atomicAdd(&lh[idx1 >> 9], 1);
            atomicAdd(&lh[idx2 >> 9], 1);
            atomicAdd(&lh[idx3 >> 9], 1);
        }
    }
    __syncthreads();
    for (int b = threadIdx.x; b < NBUCK; b += L1_THREADS) {
        int h = lh[b];
        lh[b] = h ? atomicAdd(&cursor[b], h) : 0;
    }
    __syncthreads();
#pragma unroll
    for (int it = 0; it < L1_VITERS; it++) {
        int i = base + (it * L1_THREADS + threadIdx.x) * 4;
        if (i < NNZTOT) {
            int4 c4;
            float4 v4;
            if (i < 2 * NNZ1) {
                c4 = *reinterpret_cast<const int4*>(a1c + i);
                v4 = *reinterpret_cast<const float4*>(a1v + i);
            } else {
                c4 = *reinterpret_cast<const int4*>(a2c + (i - 2 * NNZ1));
                v4 = *reinterpret_cast<const float4*>(a2v + (i - 2 * NNZ1));
            }
            int idx0 = idxv[it * 4],     idx1 = idxv[it * 4 + 1];
            int idx2 = idxv[it * 4 + 2], idx3 = idxv[it * 4 + 3];
            int p0 = atomicAdd(&lh[idx0 >> 9], 1);
            lvl1[p0] = make_int2(((idx0 & 511) << 17) | c4.x, __float_as_int(v4.x));
            int p1 = atomicAdd(&lh[idx1 >> 9], 1);
            lvl1[p1] = make_int2(((idx1 & 511) << 17) | c4.y, __float_as_int(v4.y));
            int p2 = atomicAdd(&lh[idx2 >> 9], 1);
            lvl1[p2] = make_int2(((idx2 & 511) << 17) | c4.z, __float_as_int(v4.z));
            int p3 = atomicAdd(&lh[idx3 >> 9], 1);
            lvl1[p3] = make_int2(((idx3 & 511) << 17) | c4.w, __float_as_int(v4.w));
        }
    }
}

// ---------------- level-2 sort within bucket (one block per bucket) ----------------
__global__ __launch_bounds__(512) void lvl2_sort_kernel(
        const int2* __restrict__ lvl1, const int* __restrict__ cursor,
        int* __restrict__ binned, int* __restrict__ rps, int* __restrict__ rpe) {
    extern __shared__ int2 lrec[];            // CAP records (69.6 KB)
    __shared__ int cnt[512];
    __shared__ int sc[512];
    int b = blockIdx.x;
    int t = threadIdx.x;
    int s0 = b * CAP;
    int e0 = cursor[b];
    int n  = e0 - s0;
    cnt[t] = 0;
    __syncthreads();
    for (int k = t; k < n; k += 512) {
        int2 rec = lvl1[s0 + k];
        lrec[k] = rec;
        atomicAdd(&cnt[rec.x >> 17], 1);
    }
    __syncthreads();
    int v = cnt[t];
    sc[t] = v;
    __syncthreads();
    for (int off = 1; off < 512; off <<= 1) {
        int y = (t >= off) ? sc[t - off] : 0;
        __syncthreads();
        sc[t] += y;
        __syncthreads();
    }
    int incl = sc[t];
    int excl = incl - v;
    int idx = (b << 9) + t;
    if (idx < NTOT) {
        rps[idx] = s0 + excl;
        rpe[idx] = s0 + incl;
    }
    cnt[t] = excl;   // repurpose as local cursor
    __syncthreads();
    for (int k = t; k < n; k += 512) {
        int2 rec = lrec[k];
        int rl  = rec.x >> 17;
        int col = rec.x & 0x1FFFF;
        unsigned hv = __half_as_ushort(__float2half(__int_as_float(rec.y)));
        int pos = atomicAdd(&cnt[rl], 1);
        binned[s0 + pos] = (int)((hv << 17) | (unsigned)col);
    }
}

// ---------------- fused GCN row kernel: ONE launch, 3 block classes ----------------
// Quarter-wave fp16 gather: 16 lanes x 16 B (8 fp16) per edge, 8 in flight.
// Plain cached loads on edge records (r16 lesson: NT there hurts).
// Block classes: d-rows [0,D_BLOCKS) emb1 -> out_d; med [D,D+M) BOTH graphs
// -> out_m = t*r1+(1-t)*r2 pure store (no RMW, no ordering dep);
// p-rows [D+M, D+M+P) emb2 -> out_p.

__device__ __forceinline__ void fma8(float acc[8], float v, int4 h) {
    union U { int4 i; __half2 h2[4]; } u;
    u.i = h;
#pragma unroll
    for (int j = 0; j < 4; j++) {
        float2 f = __half22float2(u.h2[j]);
        acc[2 * j]     = fmaf(v, f.x, acc[2 * j]);
        acc[2 * j + 1] = fmaf(v, f.y, acc[2 * j + 1]);
    }
}

__device__ __forceinline__ float rec_val(unsigned rec) {
    return __half2float(__ushort_as_half((unsigned short)(rec >> 17)));
}

__device__ __forceinline__ void gather8(int s, int e,
                                        const int* __restrict__ binned,
                                        int q, int sub16,
                                        const ushort_t* __restrict__ emb,
                                        float acc[8]) {
    int k = s + q;
    for (; k + 4 < e; k += 8) {
        unsigned r0 = (unsigned)binned[k];
        unsigned r1 = (unsigned)binned[k + 4];
        const int4* b0 = reinterpret_cast<const int4*>(emb + ((size_t)(r0 & 0x1FFFFu) << 7));
        const int4* b1 = reinterpret_cast<const int4*>(emb + ((size_t)(r1 & 0x1FFFFu) << 7));
        int4 h0 = b0[sub16];
        int4 h1 = b1[sub16];
        fma8(acc, rec_val(r0), h0);
        fma8(acc, rec_val(r1), h1);
    }
    for (; k < e; k += 4) {
        unsigned r0 = (unsigned)binned[k];
        const int4* b0 = reinterpret_cast<const int4*>(emb + ((size_t)(r0 & 0x1FFFFu) << 7));
        int4 h0 = b0[sub16];
        fma8(acc, rec_val(r0), h0);
    }
}

// gathers two spans, reduces quarters, returns r[j] = 2*(relu(A)+relu(B))
__device__ __forceinline__ void row_pair(int iA, int iB,
                                         const int* __restrict__ rps,
                                         const int* __restrict__ rpe,
                                         const int* __restrict__ binned,
                                         int q, int sub16,
                                         const ushort_t* __restrict__ emb,
                                         float r[8]) {
    float aA[8] = {0, 0, 0, 0, 0, 0, 0, 0};
    float aB[8] = {0, 0, 0, 0, 0, 0, 0, 0};
    gather8(rps[iA], rpe[iA], binned, q, sub16, emb, aA);
    gather8(rps[iB], rpe[iB], binned, q, sub16, emb, aB);
#pragma unroll
    for (int j = 0; j < 8; j++) {
        aA[j] += __shfl_xor(aA[j], 16);
        aA[j] += __shfl_xor(aA[j], 32);
        aB[j] += __shfl_xor(aB[j], 16);
        aB[j] += __shfl_xor(aB[j], 32);
        r[j] = 2.f * (fmaxf(aA[j], 0.f) + fmaxf(aB[j], 0.f));
    }
}

__global__ __launch_bounds__(256) void fused_gcn_kernel(
        const int* __restrict__ rps, const int* __restrict__ rpe,
        const int* __restrict__ binned,
        const ushort_t* __restrict__ emb1, const ushort_t* __restrict__ emb2,
        const float* __restrict__ inter,
        float* __restrict__ out_d, float* __restrict__ out_p,
        float* __restrict__ out_m) {
    int bid   = blockIdx.x;
    int wv    = threadIdx.x >> 6;
    int lane  = threadIdx.x & 63;
    int q     = lane >> 4;
    int sub16 = lane & 15;

    if (bid < D_BLOCKS) {
        int r = bid * 4 + wv;
        float res[8];
        row_pair(r, N1 + r, rps, rpe, binned, q, sub16, emb1, res);
        if (lane >= 16) return;
        float4* dst = reinterpret_cast<float4*>(out_d + (size_t)r * FEATDIM);
        dst[sub16 * 2]     = make_float4(res[0], res[1], res[2], res[3]);
        dst[sub16 * 2 + 1] = make_float4(res[4], res[5], res[6], res[7]);
    } else if (bid < D_BLOCKS + M_BLOCKS) {
        int m = (bid - D_BLOCKS) * 4 + wv;
        float r1[8], r2[8];
        row_pair(DIAGNUM + m, N1 + DIAGNUM + m, rps, rpe, binned, q, sub16, emb1, r1);
        row_pair(2 * N1 + PRONUM + m, 2 * N1 + N2 + PRONUM + m,
                 rps, rpe, binned, q, sub16, emb2, r2);
        if (lane >= 16) return;
        float t = *inter;
        float res[8];
#pragma unroll
        for (int j = 0; j < 8; j++)
            res[j] = fmaf(t, r1[j] - r2[j], r2[j]);   // t*r1 + (1-t)*r2
        float4* dst = reinterpret_cast<float4*>(out_m + (size_t)m * FEATDIM);
        dst[sub16 * 2]     = make_float4(res[0], res[1], res[2], res[3]);
        dst[sub16 * 2 + 1] = make_float4(res[4], res[5], res[6], res[7]);
    } else {
        int r = (bid - D_BLOCKS - M_BLOCKS) * 4 + wv;
        float res[8];
        row_pair(2 * N1 + r, 2 * N1 + N2 + r, rps, rpe, binned, q, sub16, emb2, res);
        if (lane >= 16) return;
        float4* dst = reinterpret_cast<float4*>(out_p + (size_t)r * FEATDIM);
        dst[sub16 * 2]     = make_float4(res[0], res[1], res[2], res[3]);
        dst[sub16 * 2 + 1] = make_float4(res[4], res[5], res[6], res[7]);
    }
}

// ---------------- host orchestration ----------------

extern "C" void kernel_launch(void* const* d_in, const int* in_sizes, int n_in,
                              void* d_out, int out_size, void* d_ws, size_t ws_size,
                              hipStream_t stream) {
    const int*   a1r = (const int*)d_in[0];
    const int*   a1c = (const int*)d_in[1];
    const float* a1v = (const float*)d_in[2];
    const int*   a2r = (const int*)d_in[3];
    const int*   a2c = (const int*)d_in[4];
    const float* a2v = (const float*)d_in[5];
    const float* dE  = (const float*)d_in[6];
    const float* mE  = (const float*)d_in[7];
    const float* pE  = (const float*)d_in[8];
    const float* inter = (const float*)d_in[9];

    float* out   = (float*)d_out;
    float* out_m = out;                               // 20000*128
    float* out_d = out + (size_t)MEDNUM * FEATDIM;    // 50000*128
    float* out_p = out_d + (size_t)DIAGNUM * FEATDIM; // 40000*128

    const size_t SZ_BINNED = (size_t)NBUCK * CAP * 4;    // 17.69 MB
    const size_t SZ_LVL1   = (size_t)NBUCK * CAP * 8;    // 35.37 MB
    const size_t SZ_EMB    = (size_t)(N1 + N2) * FEATDIM * 2;  // 33.28 MB
    const size_t SZ_MISC   = (size_t)NTOT * 8 + (size_t)NBUCK * 4 + 64;

    const int BLK = 256;

    char* ws = (char*)d_ws;
    int* binned = (int*)ws;          ws += SZ_BINNED;

    bool bigws = ws_size >= SZ_BINNED + SZ_LVL1 + SZ_EMB + SZ_MISC;

    int2*     lvl1;
    ushort_t* emb1;
    if (bigws) {
        lvl1 = (int2*)ws;            ws += SZ_LVL1;
        emb1 = (ushort_t*)ws;        ws += SZ_EMB;     // separate region
    } else {
        lvl1 = (int2*)ws;                              // aliased: lvl1 then emb
        emb1 = (ushort_t*)ws;        ws += SZ_LVL1;
    }
    ushort_t* emb2 = emb1 + (size_t)N1 * FEATDIM;
    int* rps    = (int*)ws;          ws += (size_t)NTOT * 4;
    int* rpe    = (int*)ws;          ws += (size_t)NTOT * 4;
    int* cursor = (int*)ws;          ws += (size_t)NBUCK * 4;

    init_cursor_kernel<<<(NBUCK + BLK - 1) / BLK, BLK, 0, stream>>>(cursor);

    if (bigws) {
        // conversion runs as tail blocks of the lvl1 launch (separate regions)
        lvl1_scatter_kernel<<<L1_BLOCKS + CONV_BLOCKS, L1_THREADS, 0, stream>>>(
            a1r, a1c, a1v, a2r, a2c, a2v, cursor, lvl1, dE, mE, pE, emb1, emb2);
        lvl2_sort_kernel<<<NBUCK, 512, (size_t)CAP * sizeof(int2), stream>>>(
            lvl1, cursor, binned, rps, rpe);
    } else {
        lvl1_scatter_kernel<<<L1_BLOCKS, L1_THREADS, 0, stream>>>(
            a1r, a1c, a1v, a2r, a2c, a2v, cursor, lvl1, dE, mE, pE, emb1, emb2);
        lvl2_sort_kernel<<<NBUCK, 512, (size_t)CAP * sizeof(int2), stream>>>(
            lvl1, cursor, binned, rps, rpe);
        // aliased mode: lvl1 records dead now; region becomes fp16 embeddings
        convert_emb_kernel<<<(TOT8 + BLK - 1) / BLK, BLK, 0, stream>>>(
            dE, mE, pE, emb1, emb2);
    }

    // single fused launch: d-rows, med-rows (both graphs), p-rows
    fused_gcn_kernel<<<D_BLOCKS + M_BLOCKS + P_BLOCKS, BLK, 0, stream>>>(
        rps, rpe, binned, emb1, emb2, inter, out_d, out_p, out_m);
}

// Round 20
// 215.824 us; speedup vs baseline: 1.0637x; 1.0637x over previous
//
#include <hip/hip_runtime.h>
#include <hip/hip_fp16.h>

#define DIAGNUM 50000
#define MEDNUM  20000
#define PRONUM  40000
#define FEATDIM 128
#define N1 (DIAGNUM + MEDNUM)   // 70000
#define N2 (PRONUM + MEDNUM)    // 60000
#define NNZ1 1120000
#define NNZ2 960000
#define NTOT (2 * N1 + 2 * N2)            // 260000 concatenated rows
#define NNZTOT (2 * NNZ1 + 2 * NNZ2)      // 4160000 concatenated edges
#define NBUCK ((NTOT + 511) >> 9)         // 508 buckets of 512 rows
#define CAP 8704                           // bucket capacity (mean 8192, +5.7 sigma)
#define L1_THREADS 512
#define L1_CHUNK 8192
#define L1_VITERS (L1_CHUNK / (L1_THREADS * 4))   // 4 iterations of 4 edges
#define L1_BLOCKS ((NNZTOT + L1_CHUNK - 1) / L1_CHUNK)   // 508

typedef unsigned short ushort_t;

// ---------------- cursor init (bucket bases are fixed: b*CAP) ----------------
__global__ __launch_bounds__(256) void init_cursor_kernel(int* __restrict__ cursor) {
    int b = blockIdx.x * 256 + threadIdx.x;
    if (b < NBUCK) cursor[b] = b * CAP;
}

// ---------------- level-1 scatter into fixed-capacity buckets ----------------
// 512 threads x 8192-edge chunks; each thread owns 4 CONSECUTIVE edges per
// iteration (int4/float4 vector loads — NNZ1/NNZ2 divisible by 4, chunks
// aligned, so vectors never straddle arrays). Row indices cached in registers
// across sweeps. record: .x = (row_local << 17) | col, .y = val bits.
__global__ __launch_bounds__(L1_THREADS) void lvl1_scatter_kernel(
        const int* __restrict__ a1r, const int* __restrict__ a1c,
        const float* __restrict__ a1v,
        const int* __restrict__ a2r, const int* __restrict__ a2c,
        const float* __restrict__ a2v,
        int* __restrict__ cursor, int2* __restrict__ lvl1) {
    __shared__ int lh[NBUCK];
    for (int b = threadIdx.x; b < NBUCK; b += L1_THREADS) lh[b] = 0;
    __syncthreads();
    int base = blockIdx.x * L1_CHUNK;
    int idxv[L1_VITERS * 4];
    // sweep 1: block-local bucket histogram (vector row loads, cache idx)
#pragma unroll
    for (int it = 0; it < L1_VITERS; it++) {
        int i = base + (it * L1_THREADS + threadIdx.x) * 4;
        if (i < NNZTOT) {
            int4 r4;
            int ofs;
            if (i < 2 * NNZ1) {
                r4 = *reinterpret_cast<const int4*>(a1r + i);
                ofs = (i < NNZ1) ? 0 : N1;
            } else {
                r4 = *reinterpret_cast<const int4*>(a2r + (i - 2 * NNZ1));
                ofs = 2 * N1 + ((i - 2 * NNZ1 < NNZ2) ? 0 : N2);
            }
            int idx0 = ofs + r4.x, idx1 = ofs + r4.y;
            int idx2 = ofs + r4.z, idx3 = ofs + r4.w;
            idxv[it * 4]     = idx0;
            idxv[it * 4 + 1] = idx1;
            idxv[it * 4 + 2] = idx2;
            idxv[it * 4 + 3] = idx3;
            atomicAdd(&lh[idx0 >> 9], 1);
            atomicAdd(&lh[idx1 >> 9], 1);
            atomicAdd(&lh[idx2 >> 9], 1);
            atomicAdd(&lh[idx3 >> 9], 1);
        }
    }
    __syncthreads();
    // reserve spans: lh[b] becomes this block's rolling global cursor
    for (int b = threadIdx.x; b < NBUCK; b += L1_THREADS) {
        int h = lh[b];
        lh[b] = h ? atomicAdd(&cursor[b], h) : 0;
    }
    __syncthreads();
    // sweep 2: write records (vector col/val loads; idx from registers)
#pragma unroll
    for (int it = 0; it < L1_VITERS; it++) {
        int i = base + (it * L1_THREADS + threadIdx.x) * 4;
        if (i < NNZTOT) {
            int4 c4;
            float4 v4;
            if (i < 2 * NNZ1) {
                c4 = *reinterpret_cast<const int4*>(a1c + i);
                v4 = *reinterpret_cast<const float4*>(a1v + i);
            } else {
                c4 = *reinterpret_cast<const int4*>(a2c + (i - 2 * NNZ1));
                v4 = *reinterpret_cast<const float4*>(a2v + (i - 2 * NNZ1));
            }
            int idx0 = idxv[it * 4],     idx1 = idxv[it * 4 + 1];
            int idx2 = idxv[it * 4 + 2], idx3 = idxv[it * 4 + 3];
            int p0 = atomicAdd(&lh[idx0 >> 9], 1);
            lvl1[p0] = make_int2(((idx0 & 511) << 17) | c4.x, __float_as_int(v4.x));
            int p1 = atomicAdd(&lh[idx1 >> 9], 1);
            lvl1[p1] = make_int2(((idx1 & 511) << 17) | c4.y, __float_as_int(v4.y));
            int p2 = atomicAdd(&lh[idx2 >> 9], 1);
            lvl1[p2] = make_int2(((idx2 & 511) << 17) | c4.z, __float_as_int(v4.z));
            int p3 = atomicAdd(&lh[idx3 >> 9], 1);
            lvl1[p3] = make_int2(((idx3 & 511) << 17) | c4.w, __float_as_int(v4.w));
        }
    }
}

// ---------------- level-2 sort within bucket (one block per bucket) ----------------
// Bucket records staged in dynamic LDS during the histogram sweep -> lvl1 read
// ONCE from global. Block exclusively owns [b*CAP, cursor[b]) -> clean writes.
// Emits per-row spans rps/rpe. Final record: 4 B = (fp16(val) << 17) | col.
__global__ __launch_bounds__(512) void lvl2_sort_kernel(
        const int2* __restrict__ lvl1, const int* __restrict__ cursor,
        int* __restrict__ binned, int* __restrict__ rps, int* __restrict__ rpe) {
    extern __shared__ int2 lrec[];            // CAP records (69.6 KB)
    __shared__ int cnt[512];
    __shared__ int sc[512];
    int b = blockIdx.x;
    int t = threadIdx.x;
    int s0 = b * CAP;
    int e0 = cursor[b];   // after lvl1: end of bucket fill
    int n  = e0 - s0;
    cnt[t] = 0;
    __syncthreads();
    // sweep 1: stage to LDS + histogram
    for (int k = t; k < n; k += 512) {
        int2 rec = lvl1[s0 + k];
        lrec[k] = rec;
        atomicAdd(&cnt[rec.x >> 17], 1);
    }
    __syncthreads();
    int v = cnt[t];
    sc[t] = v;
    __syncthreads();
    for (int off = 1; off < 512; off <<= 1) {
        int y = (t >= off) ? sc[t - off] : 0;
        __syncthreads();
        sc[t] += y;
        __syncthreads();
    }
    int incl = sc[t];
    int excl = incl - v;
    int idx = (b << 9) + t;
    if (idx < NTOT) {
        rps[idx] = s0 + excl;
        rpe[idx] = s0 + incl;
    }
    cnt[t] = excl;   // repurpose as local cursor
    __syncthreads();
    // sweep 2: scatter from LDS to sorted global positions
    for (int k = t; k < n; k += 512) {
        int2 rec = lrec[k];
        int rl  = rec.x >> 17;
        int col = rec.x & 0x1FFFF;
        unsigned hv = __half_as_ushort(__float2half(__int_as_float(rec.y)));
        int pos = atomicAdd(&cnt[rl], 1);
        binned[s0 + pos] = (int)((hv << 17) | (unsigned)col);
    }
}

// ---------------- fp16 embedding conversion (unified per-graph layouts) ----------------
// emb1 = [dE; mE] (N1 x 128), emb2 = [pE; mE] (N2 x 128); med rows duplicated.
#define TOT8 ((DIAGNUM + MEDNUM + PRONUM) * (FEATDIM / 8))   // 1,760,000

__device__ __forceinline__ ushort_t f2h(float x) {
    return __half_as_ushort(__float2half(x));
}

__global__ __launch_bounds__(256) void convert_emb_kernel(
        const float* __restrict__ dE, const float* __restrict__ mE,
        const float* __restrict__ pE,
        ushort_t* __restrict__ emb1, ushort_t* __restrict__ emb2) {
    int t8 = blockIdx.x * 256 + threadIdx.x;
    if (t8 >= TOT8) return;
    long flat = (long)t8 * 8;
    const float* src;
    ushort_t* dst;
    ushort_t* dst2 = nullptr;
    if (flat < (long)DIAGNUM * FEATDIM) {
        src = dE + flat;
        dst = emb1 + flat;
    } else if (flat < (long)(DIAGNUM + MEDNUM) * FEATDIM) {
        long o = flat - (long)DIAGNUM * FEATDIM;
        src = mE + o;
        dst  = emb1 + (long)DIAGNUM * FEATDIM + o;
        dst2 = emb2 + (long)PRONUM * FEATDIM + o;
    } else {
        long o = flat - (long)(DIAGNUM + MEDNUM) * FEATDIM;
        src = pE + o;
        dst = emb2 + o;
    }
    float4 a = *reinterpret_cast<const float4*>(src);
    float4 b = *reinterpret_cast<const float4*>(src + 4);
    int4 w;
    w.x = (int)((unsigned)f2h(a.x) | ((unsigned)f2h(a.y) << 16));
    w.y = (int)((unsigned)f2h(a.z) | ((unsigned)f2h(a.w) << 16));
    w.z = (int)((unsigned)f2h(b.x) | ((unsigned)f2h(b.y) << 16));
    w.w = (int)((unsigned)f2h(b.z) | ((unsigned)f2h(b.w) << 16));
    *reinterpret_cast<int4*>(dst) = w;
    if (dst2) *reinterpret_cast<int4*>(dst2) = w;
}

// ---------------- fused GCN row kernel (quarter-wave fp16 gather, 2x unroll) ----------------
// 16 lanes x 16 B (8 fp16) per edge, 8 edges in flight per wave.
// Plain (cached) loads on edge records — each 64 B line holds 16 records
// consumed across iterations, so caching them is essential (round-16 lesson).

__device__ __forceinline__ void fma8(float acc[8], float v, int4 h) {
    union U { int4 i; __half2 h2[4]; } u;
    u.i = h;
#pragma unroll
    for (int j = 0; j < 4; j++) {
        float2 f = __half22float2(u.h2[j]);
        acc[2 * j]     = fmaf(v, f.x, acc[2 * j]);
        acc[2 * j + 1] = fmaf(v, f.y, acc[2 * j + 1]);
    }
}

__device__ __forceinline__ float rec_val(unsigned rec) {
    return __half2float(__ushort_as_half((unsigned short)(rec >> 17)));
}

__device__ __forceinline__ void gather8(int s, int e,
                                        const int* __restrict__ binned,
                                        int q, int sub16,
                                        const ushort_t* __restrict__ emb,
                                        float acc[8]) {
    int k = s + q;
    for (; k + 4 < e; k += 8) {
        unsigned r0 = (unsigned)binned[k];
        unsigned r1 = (unsigned)binned[k + 4];
        const int4* b0 = reinterpret_cast<const int4*>(emb + ((size_t)(r0 & 0x1FFFFu) << 7));
        const int4* b1 = reinterpret_cast<const int4*>(emb + ((size_t)(r1 & 0x1FFFFu) << 7));
        int4 h0 = b0[sub16];
        int4 h1 = b1[sub16];
        fma8(acc, rec_val(r0), h0);
        fma8(acc, rec_val(r1), h1);
    }
    for (; k < e; k += 4) {
        unsigned r0 = (unsigned)binned[k];
        const int4* b0 = reinterpret_cast<const int4*>(emb + ((size_t)(r0 & 0x1FFFFu) << 7));
        int4 h0 = b0[sub16];
        fma8(acc, rec_val(r0), h0);
    }
}

// One 64-lane wave per output row of ONE graph.
// graph==0 (graph2): med rows -> out_m = (1-t)*res (pure write)
// graph==1 (graph1): med rows -> out_m += t*res    (after graph2 launch)
__global__ __launch_bounds__(256) void fused_gcn_kernel(
        const int* __restrict__ rps, const int* __restrict__ rpe,
        const int* __restrict__ binned,
        const ushort_t* __restrict__ emb,   // unified layout for this graph
        const float* __restrict__ inter,
        float* __restrict__ out_d, float* __restrict__ out_p,
        float* __restrict__ out_m, int graph) {
    int gtid = blockIdx.x * blockDim.x + threadIdx.x;
    int w     = gtid >> 6;
    int lane  = gtid & 63;
    int q     = lane >> 4;
    int sub16 = lane & 15;

    int iA, iB, nrows;
    if (graph) { nrows = N1; iA = w;          iB = N1 + w; }
    else       { nrows = N2; iA = 2 * N1 + w; iB = 2 * N1 + N2 + w; }
    if (w >= nrows) return;

    float aA[8] = {0, 0, 0, 0, 0, 0, 0, 0};
    float aB[8] = {0, 0, 0, 0, 0, 0, 0, 0};
    gather8(rps[iA], rpe[iA], binned, q, sub16, emb, aA);
    gather8(rps[iB], rpe[iB], binned, q, sub16, emb, aB);

    // reduce the 4 quarters
#pragma unroll
    for (int j = 0; j < 8; j++) {
        aA[j] += __shfl_xor(aA[j], 16);
        aA[j] += __shfl_xor(aA[j], 32);
        aB[j] += __shfl_xor(aB[j], 16);
        aB[j] += __shfl_xor(aB[j], 32);
    }

    if (lane >= 16) return;

    float r[8];
#pragma unroll
    for (int j = 0; j < 8; j++)
        r[j] = 2.f * (fmaxf(aA[j], 0.f) + fmaxf(aB[j], 0.f));

    float4 lo = make_float4(r[0], r[1], r[2], r[3]);
    float4 hi = make_float4(r[4], r[5], r[6], r[7]);

    if (graph) {
        if (w < DIAGNUM) {
            float4* dst = reinterpret_cast<float4*>(out_d + (size_t)w * FEATDIM);
            dst[sub16 * 2]     = lo;
            dst[sub16 * 2 + 1] = hi;
        } else {
            float t = *inter;
            float4* dst = reinterpret_cast<float4*>(
                out_m + (size_t)(w - DIAGNUM) * FEATDIM);
            float4 o0 = dst[sub16 * 2];
            float4 o1 = dst[sub16 * 2 + 1];
            o0.x = fmaf(t, lo.x, o0.x); o0.y = fmaf(t, lo.y, o0.y);
            o0.z = fmaf(t, lo.z, o0.z); o0.w = fmaf(t, lo.w, o0.w);
            o1.x = fmaf(t, hi.x, o1.x); o1.y = fmaf(t, hi.y, o1.y);
            o1.z = fmaf(t, hi.z, o1.z); o1.w = fmaf(t, hi.w, o1.w);
            dst[sub16 * 2]     = o0;
            dst[sub16 * 2 + 1] = o1;
        }
    } else {
        if (w < PRONUM) {
            float4* dst = reinterpret_cast<float4*>(out_p + (size_t)w * FEATDIM);
            dst[sub16 * 2]     = lo;
            dst[sub16 * 2 + 1] = hi;
        } else {
            float sc = 1.0f - *inter;
            lo.x *= sc; lo.y *= sc; lo.z *= sc; lo.w *= sc;
            hi.x *= sc; hi.y *= sc; hi.z *= sc; hi.w *= sc;
            float4* dst = reinterpret_cast<float4*>(
                out_m + (size_t)(w - PRONUM) * FEATDIM);
            dst[sub16 * 2]     = lo;
            dst[sub16 * 2 + 1] = hi;
        }
    }
}

// ---------------- host orchestration ----------------

extern "C" void kernel_launch(void* const* d_in, const int* in_sizes, int n_in,
                              void* d_out, int out_size, void* d_ws, size_t ws_size,
                              hipStream_t stream) {
    const int*   a1r = (const int*)d_in[0];
    const int*   a1c = (const int*)d_in[1];
    const float* a1v = (const float*)d_in[2];
    const int*   a2r = (const int*)d_in[3];
    const int*   a2c = (const int*)d_in[4];
    const float* a2v = (const float*)d_in[5];
    const float* dE  = (const float*)d_in[6];
    const float* mE  = (const float*)d_in[7];
    const float* pE  = (const float*)d_in[8];
    const float* inter = (const float*)d_in[9];

    float* out   = (float*)d_out;
    float* out_m = out;                               // 20000*128
    float* out_d = out + (size_t)MEDNUM * FEATDIM;    // 50000*128
    float* out_p = out_d + (size_t)DIAGNUM * FEATDIM; // 40000*128

    // ws layout (~55.2 MB). regionB is time-shared: lvl1 int2 records
    // (NBUCK*CAP*8 = 35.37 MB), then fp16 unified embeddings (33.28 MB) —
    // lvl1 dead after lvl2_sort.
    char* ws = (char*)d_ws;
    int* binned = (int*)ws;          ws += (size_t)NBUCK * CAP * 4;     // 17.69 MB
    char* regionB = ws;              ws += (size_t)NBUCK * CAP * 8;     // 35.37 MB
    int2*     lvl1 = (int2*)regionB;
    ushort_t* emb1 = (ushort_t*)regionB;                    // N1*128 fp16
    ushort_t* emb2 = emb1 + (size_t)N1 * FEATDIM;           // N2*128 fp16
    int* rps    = (int*)ws;          ws += (size_t)NTOT * 4;            // 1.04 MB
    int* rpe    = (int*)ws;          ws += (size_t)NTOT * 4;            // 1.04 MB
    int* cursor = (int*)ws;          ws += (size_t)NBUCK * 4;

    const int BLK = 256;

    init_cursor_kernel<<<(NBUCK + BLK - 1) / BLK, BLK, 0, stream>>>(cursor);
    lvl1_scatter_kernel<<<L1_BLOCKS, L1_THREADS, 0, stream>>>(
        a1r, a1c, a1v, a2r, a2c, a2v, cursor, lvl1);
    lvl2_sort_kernel<<<NBUCK, 512, (size_t)CAP * sizeof(int2), stream>>>(
        lvl1, cursor, binned, rps, rpe);

    // lvl1 dead now; regionB becomes fp16 embeddings
    convert_emb_kernel<<<(TOT8 + BLK - 1) / BLK, BLK, 0, stream>>>(
        dE, mE, pE, emb1, emb2);

    // graph 2 first (writes out_m pure), then graph 1 (accumulates out_m)
    fused_gcn_kernel<<<(N2 + 3) / 4, BLK, 0, stream>>>(
        rps, rpe, binned, emb2, inter, out_d, out_p, out_m, 0);
    fused_gcn_kernel<<<(N1 + 3) / 4, BLK, 0, stream>>>(
        rps, rpe, binned, emb1, inter, out_d, out_p, out_m, 1);
}